// Round 1
// baseline (299.215 us; speedup 1.0000x reference)
//
#include <hip/hip_runtime.h>
#include <hip/hip_bf16.h>
#include <stdint.h>

// Shapes (fixed by the reference setup):
// B=4, N=8, Q=256, K=1024, D_MODEL=512, H=8, Dh=64, R=8, sigma=0.05

typedef __attribute__((ext_vector_type(8))) short bf16x8;
typedef __attribute__((ext_vector_type(4))) float f32x4;

__device__ __forceinline__ unsigned short f2b(float f){
    unsigned int u = __builtin_bit_cast(unsigned int, f);
    unsigned int r = u + 0x7fffu + ((u >> 16) & 1u);   // RNE
    return (unsigned short)(r >> 16);
}

// XOR swizzle for 64-col bf16 LDS tiles (128B rows): kills the 16-way
// same-bank conflict of stride-128B ds_read_b128 (guide §6 G4 / T2).
__device__ __forceinline__ int swz(int row, int byteInRow){
    return row*128 + (byteInRow ^ ((row & 7) << 4));
}

// ---------------- weight transpose + bf16 convert: Wt[n][k] = W[k][n] -------
__global__ __launch_bounds__(256) void wt_kernel(const float* __restrict__ W,
                                                 unsigned short* __restrict__ Wt){
    __shared__ float tile[64][65];
    int kt = blockIdx.x, nt = blockIdx.y;
    int tid = threadIdx.x;
    #pragma unroll
    for(int it=0; it<16; ++it){
        int idx = it*256 + tid;
        int r = idx >> 6, c = idx & 63;
        tile[r][c] = W[(kt*64 + r)*512 + nt*64 + c];
    }
    __syncthreads();
    #pragma unroll
    for(int it=0; it<16; ++it){
        int idx = it*256 + tid;
        int r = idx >> 6, c = idx & 63;
        Wt[(nt*64 + r)*512 + kt*64 + c] = f2b(tile[c][r]);
    }
}

// ---------------- positional bias: bias[b][q][k] ----------------------------
__global__ __launch_bounds__(256) void bias_kernel(
    const float* __restrict__ qpos, const float* __restrict__ kpos,
    const float* __restrict__ Wqb, const float* __restrict__ Wkb,
    float* __restrict__ out){
    int id = blockIdx.x*256 + threadIdx.x;   // [4][256][1024]
    int b = id >> 18;
    int q = (id >> 10) & 255;
    int k = id & 1023;
    const float* q3 = qpos + (b*256 + q)*3;
    const float* k3 = kpos + (b*1024 + k)*3;
    float qx=q3[0], qy=q3[1], qz=q3[2];
    float kx=k3[0], ky=k3[1], kz=k3[2];
    float dx=qx-kx, dy=qy-ky, dz=qz-kz;
    float dist2 = dx*dx + dy*dy + dz*dz;
    float lf = 0.f;
    #pragma unroll
    for(int r=0;r<8;++r){
        float qb = qx*Wqb[r] + qy*Wqb[8+r] + qz*Wqb[16+r];
        float kb = kx*Wkb[r] + ky*Wkb[8+r] + kz*Wkb[16+r];
        lf += qb*kb;
    }
    // -dist2/(2*sigma^2) = -dist2*200 ; lf / sqrt(8)
    out[id] = -dist2*200.0f + lf*0.35355339059327373f;
}

// ---------------- GEMM: C[M][512] = A(f32)[M][512] @ W[512][512] + bias -----
// Bt is W^T as bf16 [n][k]. 128x128 tile, BK=64, 4 waves (2x2), 16x16x32 MFMA.
template<bool OUT_BF16>
__global__ __launch_bounds__(256) void gemm512(
    const float* __restrict__ A,
    const unsigned short* __restrict__ Bt,
    const float* __restrict__ bias,
    void* __restrict__ Cv){
    __shared__ alignas(16) char sm[32768];
    char* As = sm;
    char* Bs = sm + 16384;
    int m0 = blockIdx.x * 128, n0 = blockIdx.y * 128;
    int tid = threadIdx.x;
    int l = tid & 63, wid = tid >> 6;
    int wr = wid >> 1, wc = wid & 1;
    int l15 = l & 15, lg = l >> 4;

    f32x4 acc[4][4];
    const f32x4 z4 = {0.f,0.f,0.f,0.f};
    #pragma unroll
    for(int m=0;m<4;++m)
        #pragma unroll
        for(int n=0;n<4;++n) acc[m][n] = z4;

    for(int kt=0; kt<8; ++kt){
        int k0 = kt*64;
        __syncthreads();
        // stage A: 128x64 f32 -> bf16 (swizzled)
        #pragma unroll
        for(int it=0; it<8; ++it){
            int idx = it*256 + tid;          // float4 index
            int row = idx >> 4;
            int col = (idx & 15) * 4;
            float4 v = *reinterpret_cast<const float4*>(A + (m0+row)*512 + k0 + col);
            uint2 d;
            d.x = (unsigned)f2b(v.x) | ((unsigned)f2b(v.y) << 16);
            d.y = (unsigned)f2b(v.z) | ((unsigned)f2b(v.w) << 16);
            *reinterpret_cast<uint2*>(As + swz(row, col*2)) = d;
        }
        // stage B: 128x64 bf16 (swizzled)
        #pragma unroll
        for(int it=0; it<4; ++it){
            int idx = it*256 + tid;          // 16B chunk index
            int row = idx >> 3;
            int colb = (idx & 7) * 16;
            uint4 v = *reinterpret_cast<const uint4*>(Bt + (n0+row)*512 + k0 + colb/2);
            *reinterpret_cast<uint4*>(Bs + swz(row, colb)) = v;
        }
        __syncthreads();
        #pragma unroll
        for(int kk=0; kk<2; ++kk){
            bf16x8 af[4], bfr[4];
            #pragma unroll
            for(int m=0;m<4;++m)
                af[m] = *reinterpret_cast<const bf16x8*>(As + swz(wr*64 + m*16 + l15, kk*64 + lg*16));
            #pragma unroll
            for(int n=0;n<4;++n)
                bfr[n] = *reinterpret_cast<const bf16x8*>(Bs + swz(wc*64 + n*16 + l15, kk*64 + lg*16));
            #pragma unroll
            for(int m=0;m<4;++m)
                #pragma unroll
                for(int n=0;n<4;++n)
                    acc[m][n] = __builtin_amdgcn_mfma_f32_16x16x32_bf16(af[m], bfr[n], acc[m][n], 0, 0, 0);
        }
    }
    #pragma unroll
    for(int m=0;m<4;++m){
        int row = m0 + wr*64 + m*16 + lg*4;
        #pragma unroll
        for(int n=0;n<4;++n){
            int col = n0 + wc*64 + n*16 + l15;
            float bv = bias[col];
            #pragma unroll
            for(int j=0;j<4;++j){
                float val = acc[m][n][j] + bv;
                if(OUT_BF16)
                    reinterpret_cast<unsigned short*>(Cv)[(size_t)(row+j)*512 + col] = f2b(val);
                else
                    reinterpret_cast<float*>(Cv)[(size_t)(row+j)*512 + col] = val;
            }
        }
    }
}

// ---------------- flash attention: per (b,n,h,q-tile64) ---------------------
__global__ __launch_bounds__(256) void attn_kernel(
    const unsigned short* __restrict__ qp,   // [8192][512] bf16
    const unsigned short* __restrict__ kp,   // [32768][512] bf16
    const unsigned short* __restrict__ vp,   // [32768][512] bf16
    const float* __restrict__ biasb,         // [4][256][1024]
    const int* __restrict__ mask,            // [4][1024]
    float* __restrict__ ctx){                // [8192][512] f32
    __shared__ alignas(16) char sm[24576];
    char* Ks  = sm;            // [64 kpos][64 d] bf16 swizzled
    char* VTs = sm + 8192;     // [64 d][64 kpos] bf16 swizzled
    char* Ps  = sm + 16384;    // per-wave 2048B: [16 q][64 kpos] bf16 swizzled

    int qt = blockIdx.x, h = blockIdx.y, zidx = blockIdx.z;  // z = b*8+n
    int b = zidx >> 3;
    int tid = threadIdx.x, l = tid & 63, wid = tid >> 6;
    int l15 = l & 15, lg = l >> 4;

    // Q fragments straight from global (2 x 16B per lane, hoisted)
    int qrow = zidx*256 + qt*64 + wid*16 + l15;
    bf16x8 qf[2];
    #pragma unroll
    for(int kk=0;kk<2;++kk)
        qf[kk] = *reinterpret_cast<const bf16x8*>(qp + (size_t)qrow*512 + h*64 + kk*32 + lg*8);

    float mrun[4], lrun[4];
    f32x4 acc[4];
    const f32x4 z4 = {0.f,0.f,0.f,0.f};
    #pragma unroll
    for(int j=0;j<4;++j){ mrun[j] = -3.0e38f; lrun[j] = 0.f; }
    #pragma unroll
    for(int t=0;t<4;++t) acc[t] = z4;

    for(int kt=0; kt<16; ++kt){
        int kb0 = zidx*1024 + kt*64;
        __syncthreads();
        // stage K tile [64][64]
        #pragma unroll
        for(int it=0; it<2; ++it){
            int idx = it*256 + tid;
            int row = idx >> 3;
            int colb = (idx & 7) * 16;
            uint4 v = *reinterpret_cast<const uint4*>(kp + (size_t)(kb0+row)*512 + h*64 + colb/2);
            *reinterpret_cast<uint4*>(Ks + swz(row, colb)) = v;
        }
        // stage V^T tile: coalesced read of vp rows, scatter-transpose into LDS
        #pragma unroll
        for(int it=0; it<2; ++it){
            int idx = it*256 + tid;
            int vrow = idx >> 3;          // kpos within tile
            int c8 = idx & 7;
            uint4 v = *reinterpret_cast<const uint4*>(vp + (size_t)(kb0+vrow)*512 + h*64 + c8*8);
            unsigned short e[8];
            *reinterpret_cast<uint4*>(e) = v;
            #pragma unroll
            for(int j=0;j<8;++j){
                int d = c8*8 + j;
                *reinterpret_cast<unsigned short*>(VTs + swz(d, vrow*2)) = e[j];
            }
        }
        __syncthreads();

        // S = q @ K^T  (C layout: q-row = lg*4+j, k-col = t*16+l15)
        f32x4 s[4];
        #pragma unroll
        for(int t=0;t<4;++t){
            s[t] = z4;
            #pragma unroll
            for(int kk=0;kk<2;++kk){
                bf16x8 kf = *reinterpret_cast<const bf16x8*>(Ks + swz(t*16 + l15, kk*64 + lg*16));
                s[t] = __builtin_amdgcn_mfma_f32_16x16x32_bf16(qf[kk], kf, s[t], 0, 0, 0);
            }
        }
        // scale + bias + mask (exact reference semantics)
        int qg = b*256 + qt*64 + wid*16 + lg*4;
        #pragma unroll
        for(int t=0;t<4;++t){
            int kcol = kt*64 + t*16 + l15;
            int mk = mask[b*1024 + kcol];
            #pragma unroll
            for(int j=0;j<4;++j){
                float bvv = biasb[(size_t)(qg + j)*1024 + kcol];
                s[t][j] = mk ? (s[t][j]*0.125f + bvv) : -10000.0f;
            }
        }
        // online softmax
        float pmax[4];
        #pragma unroll
        for(int j=0;j<4;++j){
            float mx = fmaxf(fmaxf(s[0][j], s[1][j]), fmaxf(s[2][j], s[3][j]));
            mx = fmaxf(mx, __shfl_xor(mx, 1, 16));
            mx = fmaxf(mx, __shfl_xor(mx, 2, 16));
            mx = fmaxf(mx, __shfl_xor(mx, 4, 16));
            mx = fmaxf(mx, __shfl_xor(mx, 8, 16));
            pmax[j] = mx;
        }
        float scl[4];
        #pragma unroll
        for(int j=0;j<4;++j){
            float mn = fmaxf(mrun[j], pmax[j]);
            scl[j] = __expf(mrun[j] - mn);
            mrun[j] = mn;
        }
        float psum[4] = {0.f,0.f,0.f,0.f};
        unsigned short pb[4][4];
        #pragma unroll
        for(int t=0;t<4;++t)
            #pragma unroll
            for(int j=0;j<4;++j){
                float p = __expf(s[t][j] - mrun[j]);
                psum[j] += p;
                pb[t][j] = f2b(p);
            }
        #pragma unroll
        for(int j=0;j<4;++j){
            float ps = psum[j];
            ps += __shfl_xor(ps, 1, 16);
            ps += __shfl_xor(ps, 2, 16);
            ps += __shfl_xor(ps, 4, 16);
            ps += __shfl_xor(ps, 8, 16);
            lrun[j] = lrun[j]*scl[j] + ps;
            #pragma unroll
            for(int t=0;t<4;++t) acc[t][j] *= scl[j];
        }
        // P (C-layout) -> per-wave LDS -> A-fragments
        char* Pw = Ps + wid*2048;
        #pragma unroll
        for(int t=0;t<4;++t)
            #pragma unroll
            for(int j=0;j<4;++j)
                *reinterpret_cast<unsigned short*>(Pw + swz(lg*4 + j, (t*16 + l15)*2)) = pb[t][j];
        __syncthreads();
        // PV: acc[t] += P @ V
        #pragma unroll
        for(int kk=0;kk<2;++kk){
            bf16x8 pf = *reinterpret_cast<const bf16x8*>(Pw + swz(l15, kk*64 + lg*16));
            #pragma unroll
            for(int t=0;t<4;++t){
                bf16x8 vf = *reinterpret_cast<const bf16x8*>(VTs + swz(t*16 + l15, kk*64 + lg*16));
                acc[t] = __builtin_amdgcn_mfma_f32_16x16x32_bf16(pf, vf, acc[t], 0, 0, 0);
            }
        }
    }
    // normalize + write context (f32)
    #pragma unroll
    for(int j=0;j<4;++j){
        float rl = 1.0f / lrun[j];
        int row = zidx*256 + qt*64 + wid*16 + lg*4 + j;
        #pragma unroll
        for(int t=0;t<4;++t)
            ctx[(size_t)row*512 + h*64 + t*16 + l15] = acc[t][j] * rl;
    }
}

// ---------------------------------------------------------------------------
extern "C" void kernel_launch(void* const* d_in, const int* in_sizes, int n_in,
                              void* d_out, int out_size, void* d_ws, size_t ws_size,
                              hipStream_t stream){
    (void)in_sizes; (void)n_in; (void)out_size; (void)ws_size;
    const float* query     = (const float*)d_in[0];
    const float* key_value = (const float*)d_in[1];
    const float* query_pos = (const float*)d_in[2];
    const float* key_pos   = (const float*)d_in[3];
    const int*   key_mask  = (const int*)d_in[4];
    const float* Wq  = (const float*)d_in[5];
    const float* bq  = (const float*)d_in[6];
    const float* Wk  = (const float*)d_in[7];
    const float* bk  = (const float*)d_in[8];
    const float* Wv  = (const float*)d_in[9];
    const float* bv  = (const float*)d_in[10];
    const float* Wo  = (const float*)d_in[11];
    const float* bo  = (const float*)d_in[12];
    const float* Wqb = (const float*)d_in[13];
    const float* Wkb = (const float*)d_in[14];

    char* ws = (char*)d_ws;
    unsigned short* qp   = (unsigned short*)(ws);                    //  8 MiB
    unsigned short* kp   = (unsigned short*)(ws + 8388608);          // 32 MiB
    unsigned short* vp   = (unsigned short*)(ws + 41943040);         // 32 MiB
    float*          biasb= (float*)(ws + 75497472);                  //  4 MiB
    float*          ctx  = (float*)(ws + 79691776);                  // 16 MiB
    unsigned short* WtQ  = (unsigned short*)(ws + 96468992);         //  4x 512KiB
    unsigned short* WtK  = WtQ + 262144;
    unsigned short* WtV  = WtK + 262144;
    unsigned short* WtO  = WtV + 262144;

    wt_kernel<<<dim3(8,8), 256, 0, stream>>>(Wq, WtQ);
    wt_kernel<<<dim3(8,8), 256, 0, stream>>>(Wk, WtK);
    wt_kernel<<<dim3(8,8), 256, 0, stream>>>(Wv, WtV);
    wt_kernel<<<dim3(8,8), 256, 0, stream>>>(Wo, WtO);
    bias_kernel<<<4096, 256, 0, stream>>>(query_pos, key_pos, Wqb, Wkb, biasb);

    gemm512<true ><<<dim3( 64,4), 256, 0, stream>>>(query,     WtQ, bq, qp);
    gemm512<true ><<<dim3(256,4), 256, 0, stream>>>(key_value, WtK, bk, kp);
    gemm512<true ><<<dim3(256,4), 256, 0, stream>>>(key_value, WtV, bv, vp);

    attn_kernel<<<dim3(4,8,32), 256, 0, stream>>>(qp, kp, vp, biasb, key_mask, ctx);

    gemm512<false><<<dim3( 64,4), 256, 0, stream>>>(ctx, WtO, bo, d_out);
}